// Round 4
// baseline (483.428 us; speedup 1.0000x reference)
//
#include <hip/hip_runtime.h>
#include <cmath>
#include <cstdint>

// Shapes (fixed for this problem)
#define BB 4
#define SS 2048
#define EE 1024
#define HH 16
#define DD 64
#define ROWS (BB*SS)          // 8192
#define QKV_N (3*EE)          // 3072

using bf16x8 = __attribute__((ext_vector_type(8))) __bf16;
using bf16x4 = __attribute__((ext_vector_type(4))) __bf16;
using f32x4  = __attribute__((ext_vector_type(4))) float;
typedef __attribute__((ext_vector_type(4))) short short4v;

// log2(e) / sqrt(64): folded into Q columns in the QKV GEMM epilogue
#define SCQ 0.18033688f

__device__ inline f32x4 mfma16(bf16x8 a, bf16x8 b, f32x4 c) {
    return __builtin_amdgcn_mfma_f32_16x16x32_bf16(a, b, c, 0, 0, 0);
}

// K=16 MFMA: B-operand layout (k=4*quad+j, n=lane&15) == C/D layout ->
// exp'd S registers feed PV directly, no cross-lane movement.
// NOTE: all __builtin_amdgcn_* fenced from the host pass (R3 compile failure).
__device__ inline f32x4 mfma16k16(bf16x4 a, bf16x4 b, f32x4 c) {
#if defined(__HIP_DEVICE_COMPILE__)
#if __has_builtin(__builtin_amdgcn_mfma_f32_16x16x16bf16_1k)
    return __builtin_amdgcn_mfma_f32_16x16x16bf16_1k(
        __builtin_bit_cast(short4v, a), __builtin_bit_cast(short4v, b), c, 0, 0, 0);
#else
    f32x4 d;
    asm volatile("v_mfma_f32_16x16x16_bf16 %0, %1, %2, %3\n\ts_nop 7\n\ts_nop 3"
                 : "=v"(d)
                 : "v"(__builtin_bit_cast(short4v, a)),
                   "v"(__builtin_bit_cast(short4v, b)), "v"(c));
    return d;
#endif
#else
    return c;   // host pass: never executed on device
#endif
}

__device__ inline void load_lds16(const void* g, void* l) {
    __builtin_amdgcn_global_load_lds(
        (__attribute__((address_space(1))) void*)g,
        (__attribute__((address_space(3))) void*)l, 16, 0, 0);
}

// ---------------- cast fp32 -> bf16, vectorized ----------------
__global__ __launch_bounds__(256) void cast_f32_bf16(const float* __restrict__ in,
                                                     __bf16* __restrict__ out) {
    size_t i = ((size_t)blockIdx.x * 256 + threadIdx.x) * 4;
    float4 v = *(const float4*)(in + i);
    bf16x4 o;
    o[0] = (__bf16)v.x; o[1] = (__bf16)v.y; o[2] = (__bf16)v.z; o[3] = (__bf16)v.w;
    *(bf16x4*)(out + i) = o;
}

// ---------------- transpose + cast: in [K][N] f32 -> out [N][K] bf16 ----------------
__global__ __launch_bounds__(256) void transpose_cast(const float* __restrict__ in,
                                                      __bf16* __restrict__ out,
                                                      int K, int N) {
    __shared__ float tile[32][33];
    int n0 = blockIdx.x * 32, k0 = blockIdx.y * 32;
    int tx = threadIdx.x, ty = threadIdx.y;   // block (32,8)
#pragma unroll
    for (int i = 0; i < 4; ++i)
        tile[ty + 8 * i][tx] = in[(size_t)(k0 + ty + 8 * i) * N + n0 + tx];
    __syncthreads();
#pragma unroll
    for (int i = 0; i < 4; ++i)
        out[(size_t)(n0 + ty + 8 * i) * K + k0 + tx] = (__bf16)tile[tx][ty + 8 * i];
}

// ---------------- V transpose: qkv V-section -> vt[b][h][d][s] bf16 ----------------
__global__ __launch_bounds__(256) void build_vt(const __bf16* __restrict__ qkv,
                                                __bf16* __restrict__ vt) {
    __shared__ __bf16 tile[64 * 72];   // [s][d] padded
    const int s0 = blockIdx.x * 64, h = blockIdx.y, b = blockIdx.z;
    const int tid = threadIdx.x;
#pragma unroll
    for (int r = 0; r < 2; ++r) {
        int c = r * 256 + tid;                 // 0..511
        int s = c >> 3, dp = c & 7;
        bf16x8 v = *(const bf16x8*)(qkv + (size_t)(b * SS + s0 + s) * QKV_N + 2048 + h * 64 + dp * 8);
        *(bf16x8*)(tile + s * 72 + dp * 8) = v;
    }
    __syncthreads();
#pragma unroll
    for (int r = 0; r < 2; ++r) {
        int c = r * 256 + tid;
        int d = c >> 3, sp = c & 7;
        bf16x8 o;
#pragma unroll
        for (int i = 0; i < 8; ++i) o[i] = tile[(sp * 8 + i) * 72 + d];
        *(bf16x8*)(vt + (size_t)((b * HH + h) * 64 + d) * SS + s0 + sp * 8) = o;
    }
}

// ---------------- GEMM: C[M][N] = A[M][K] @ Bt[N][K]^T + bias ----------------
// QSCALE: multiply columns [0,EE) by SCQ (folds attention scale into Q).
template <bool OUT_BF16, bool QSCALE>
__global__ __launch_bounds__(256) void gemm_bt(const __bf16* __restrict__ A,
                                               const __bf16* __restrict__ Bt,
                                               const float* __restrict__ bias,
                                               void* __restrict__ Cout,
                                               int M, int N, int K) {
    __shared__ __bf16 As[128 * 32];
    __shared__ __bf16 Bs[128 * 32];
    const int tid  = threadIdx.x;
    const int wave = tid >> 6;
    const int lane = tid & 63;
    const int lrow = lane & 15;
    const int quad = lane >> 4;
    const int wm   = (wave >> 1) * 64;
    const int wn   = (wave & 1) * 64;
    const int tm   = blockIdx.x * 128;
    const int tn   = blockIdx.y * 128;

    f32x4 acc[4][4] = {};

    const int srow = lane >> 2;
    const int skoff = (lane & 3) * 8;

    for (int k0 = 0; k0 < K; k0 += 32) {
        __syncthreads();
#pragma unroll
        for (int i = 0; i < 2; ++i) {
            int c = wave * 2 + i;
            int row = 16 * c + srow;
            load_lds16(A + (size_t)(tm + row) * K + k0 + skoff, As + c * 512);
            load_lds16(Bt + (size_t)(tn + row) * K + k0 + skoff, Bs + c * 512);
        }
        __syncthreads();

        bf16x8 bfr[4];
#pragma unroll
        for (int ni = 0; ni < 4; ++ni)
            bfr[ni] = *(const bf16x8*)(Bs + (wn + ni * 16 + lrow) * 32 + quad * 8);
#pragma unroll
        for (int mi = 0; mi < 4; ++mi) {
            bf16x8 a = *(const bf16x8*)(As + (wm + mi * 16 + lrow) * 32 + quad * 8);
#pragma unroll
            for (int ni = 0; ni < 4; ++ni)
                acc[mi][ni] = mfma16(a, bfr[ni], acc[mi][ni]);
        }
    }

#pragma unroll
    for (int ni = 0; ni < 4; ++ni) {
        int cn = tn + wn + ni * 16 + lrow;
        float bv = bias[cn];
        float sc = (QSCALE && cn < EE) ? SCQ : 1.0f;
#pragma unroll
        for (int mi = 0; mi < 4; ++mi) {
#pragma unroll
            for (int r = 0; r < 4; ++r) {
                int gm = tm + wm + mi * 16 + quad * 4 + r;
                float v = (acc[mi][ni][r] + bv) * sc;
                if (OUT_BF16)
                    ((__bf16*)Cout)[(size_t)gm * N + cn] = (__bf16)v;
                else
                    ((float*)Cout)[(size_t)gm * N + cn] = v;
            }
        }
    }
}

// ---------------- Flash attention v3 ----------------
// S^T/O^T formulation; 128 q per block (2 groups/wave), 128 keys per iter,
// K=16 PV consuming S registers directly (no P LDS round-trip).
// qkv: [B*S][3E] bf16 (Q pre-scaled by SCQ); vt: [B][H][64 d][2048 s] bf16.
__global__ __launch_bounds__(256, 3) void attn3(const __bf16* __restrict__ qkv,
                                                const __bf16* __restrict__ vt,
                                                __bf16* __restrict__ y) {
    const int qt = gridDim.x - 1 - blockIdx.x;   // heavy blocks dispatch first
    const int h = blockIdx.y, b = blockIdx.z;
    const int tid = threadIdx.x;
    const int wave = tid >> 6, lane = tid & 63;
    const int lrow = lane & 15, quad = lane >> 4;
    const int qbase = qt * 128;

    __shared__ __bf16 Klds[128 * 64];   // [key][d-chunk8 ^ (key&7)]     16 KB
    __shared__ __bf16 Vlds[64 * 128];   // [d][k-chunk8 ^ (d&7), bit3 thru] 16 KB

    const __bf16* kbase = qkv + (size_t)b * SS * QKV_N + 1024 + h * 64;
    const __bf16* vbase = vt + (size_t)(b * HH + h) * 64 * SS;

    // Q fragments (B-operand): q col = lrow; group g covers rows qbase+64g+16w+lrow
    bf16x8 qf[2][2];
#pragma unroll
    for (int g = 0; g < 2; ++g) {
        const __bf16* qp = qkv + (size_t)(b * SS + qbase + 64 * g + wave * 16 + lrow) * QKV_N + h * 64;
        qf[g][0] = *(const bf16x8*)(qp + quad * 8);
        qf[g][1] = *(const bf16x8*)(qp + 32 + quad * 8);
    }
    const int q0 = qbase + wave * 16 + lrow;   // group-0 q row for this lane's S col

    float m[2] = {-INFINITY, -INFINITY}, l[2] = {0.f, 0.f};
    f32x4 oacc[2][4] = {};   // O^T: d = 16*td + 4*quad + r, q col = lrow

    for (int kb_i = 0; kb_i <= qt; ++kb_i) {
        const int kb = kb_i * 128;
        __syncthreads();
#pragma unroll
        for (int r = 0; r < 4; ++r) {          // stage K: 128 rows x 64 d
            int c = r * 256 + tid;
            int row = c >> 3;
            int g8 = ((c & 7) ^ (row & 7)) * 8;
            load_lds16(kbase + (size_t)(kb + row) * QKV_N + g8, Klds + c * 8);
        }
#pragma unroll
        for (int r = 0; r < 4; ++r) {          // stage V^T: 64 rows x 128 keys
            int c = r * 256 + tid;
            int d = c >> 4, kc = c & 15;
            int g8 = ((kc & 8) | ((kc & 7) ^ (d & 7))) * 8;
            load_lds16(vbase + (size_t)d * SS + kb + g8, Vlds + c * 8);
        }
        __syncthreads();

        // QK^T for both q-groups (K frags shared)
        f32x4 s0[8], s1[8];
#pragma unroll
        for (int t = 0; t < 8; ++t) {
            const __bf16* kr = Klds + (16 * t + lrow) * 64;
            bf16x8 kf0 = *(const bf16x8*)(kr + 8 * (quad ^ (lrow & 7)));
            bf16x8 kf1 = *(const bf16x8*)(kr + 8 * ((4 + quad) ^ (lrow & 7)));
            f32x4 a = {};
            a = mfma16(kf0, qf[0][0], a);
            a = mfma16(kf1, qf[0][1], a);
            s0[t] = a;
            f32x4 c = {};
            c = mfma16(kf0, qf[1][0], c);
            c = mfma16(kf1, qf[1][1], c);
            s1[t] = c;
        }

        if (kb_i == qt) {   // diagonal block: causal mask
#pragma unroll
            for (int t = 0; t < 8; ++t)
#pragma unroll
                for (int r = 0; r < 4; ++r) {
                    int key = kb + 16 * t + 4 * quad + r;
                    if (key > q0)      s0[t][r] = -INFINITY;
                    if (key > q0 + 64) s1[t][r] = -INFINITY;
                }
        }

        // online softmax per group (stats per q col = lrow; 2 shuffles each)
        bf16x4 p0[8], p1[8];
#pragma unroll
        for (int g = 0; g < 2; ++g) {
            f32x4* s = g ? s1 : s0;
            bf16x4* p = g ? p1 : p0;
            float mx = -INFINITY;
#pragma unroll
            for (int t = 0; t < 8; ++t) {
                float a = fmaxf(fmaxf(s[t][0], s[t][1]), fmaxf(s[t][2], s[t][3]));
                mx = fmaxf(mx, a);
            }
            mx = fmaxf(mx, __shfl_xor(mx, 16));
            mx = fmaxf(mx, __shfl_xor(mx, 32));
            float mnew = fmaxf(m[g], mx);
            float alpha = exp2f(m[g] - mnew);
            m[g] = mnew;
            float rs = 0.f;
#pragma unroll
            for (int t = 0; t < 8; ++t) {
#pragma unroll
                for (int r = 0; r < 4; ++r) {
                    float e = exp2f(s[t][r] - mnew);
                    rs += e;
                    p[t][r] = (__bf16)e;
                }
            }
            rs += __shfl_xor(rs, 16);
            rs += __shfl_xor(rs, 32);
            l[g] = l[g] * alpha + rs;
#pragma unroll
            for (int td = 0; td < 4; ++td) {
                oacc[g][td][0] *= alpha; oacc[g][td][1] *= alpha;
                oacc[g][td][2] *= alpha; oacc[g][td][3] *= alpha;
            }
        }

        // PV: O^T += V^T P^T, K=16 per key-tile; V frags shared across groups
#pragma unroll
        for (int t = 0; t < 8; ++t) {
            int klog = 2 * t + (quad >> 1);
            int c = (klog & 8) | ((klog & 7) ^ (lrow & 7));
            const __bf16* vcol = Vlds + (size_t)lrow * 128 + c * 8 + 4 * (quad & 1);
#pragma unroll
            for (int td = 0; td < 4; ++td) {
                bf16x4 vf = *(const bf16x4*)(vcol + td * 16 * 128);
                oacc[0][td] = mfma16k16(vf, p0[t], oacc[0][td]);
                oacc[1][td] = mfma16k16(vf, p1[t], oacc[1][td]);
            }
        }
    }

    // epilogue: y[q][h*64 + 16*td + 4*quad + r], packed 8B stores
#pragma unroll
    for (int g = 0; g < 2; ++g) {
        float linv = 1.f / l[g];
        __bf16* yp = y + (size_t)(b * SS + qbase + 64 * g + wave * 16 + lrow) * EE + h * 64;
#pragma unroll
        for (int td = 0; td < 4; ++td) {
            bf16x4 o;
#pragma unroll
            for (int r = 0; r < 4; ++r) o[r] = (__bf16)(oacc[g][td][r] * linv);
            *(bf16x4*)(yp + 16 * td + 4 * quad) = o;
        }
    }
}

// ---------------- launch ----------------
extern "C" void kernel_launch(void* const* d_in, const int* in_sizes, int n_in,
                              void* d_out, int out_size, void* d_ws, size_t ws_size,
                              hipStream_t stream) {
    const float* x      = (const float*)d_in[0];
    const float* w_qkv  = (const float*)d_in[1];
    const float* b_qkv  = (const float*)d_in[2];
    const float* w_proj = (const float*)d_in[3];
    const float* b_proj = (const float*)d_in[4];
    float* out = (float*)d_out;

    __bf16* xb     = (__bf16*)d_ws;                      // 16 MB (reused as vt later)
    __bf16* wqkvT  = xb + (size_t)ROWS * EE;             // [3072][1024]
    __bf16* wprojT = wqkvT + (size_t)QKV_N * EE;         // [1024][1024]
    __bf16* qkv    = wprojT + (size_t)EE * EE;           // [8192][3072]
    __bf16* yb     = qkv + (size_t)ROWS * QKV_N;         // [8192][1024]
    __bf16* vtb    = xb;                                 // alias: xb dead after GEMM1

    cast_f32_bf16<<<dim3(ROWS * EE / 1024), dim3(256), 0, stream>>>(x, xb);
    transpose_cast<<<dim3(QKV_N / 32, EE / 32), dim3(32, 8), 0, stream>>>(w_qkv, wqkvT, EE, QKV_N);
    transpose_cast<<<dim3(EE / 32, EE / 32), dim3(32, 8), 0, stream>>>(w_proj, wprojT, EE, EE);
    gemm_bt<true, true><<<dim3(ROWS / 128, QKV_N / 128), dim3(256), 0, stream>>>(
        xb, wqkvT, b_qkv, (void*)qkv, ROWS, QKV_N, EE);
    build_vt<<<dim3(SS / 64, HH, BB), dim3(256), 0, stream>>>(qkv, vtb);
    attn3<<<dim3(SS / 128, HH, BB), dim3(256), 0, stream>>>(qkv, vtb, yb);
    gemm_bt<false, false><<<dim3(ROWS / 128, EE / 128), dim3(256), 0, stream>>>(
        yb, wprojT, b_proj, (void*)out, ROWS, EE, EE);
}

// Round 5
// 378.081 us; speedup vs baseline: 1.2786x; 1.2786x over previous
//
#include <hip/hip_runtime.h>
#include <cmath>
#include <cstdint>

// Shapes (fixed for this problem)
#define BB 4
#define SS 2048
#define EE 1024
#define HH 16
#define DD 64
#define ROWS (BB*SS)          // 8192
#define QKV_N (3*EE)          // 3072

using bf16x8 = __attribute__((ext_vector_type(8))) __bf16;
using bf16x4 = __attribute__((ext_vector_type(4))) __bf16;
using f32x4  = __attribute__((ext_vector_type(4))) float;
typedef __attribute__((ext_vector_type(4))) short short4v;

// log2(e) / sqrt(64): folded into Q columns in the QKV GEMM epilogue
#define SCQ 0.18033688f

__device__ inline f32x4 mfma16(bf16x8 a, bf16x8 b, f32x4 c) {
    return __builtin_amdgcn_mfma_f32_16x16x32_bf16(a, b, c, 0, 0, 0);
}

// K=16 MFMA: B-operand layout (k=4*quad+j, n=lane&15) == C/D layout ->
// exp'd S registers feed PV directly, no cross-lane movement. (verified R4: passed)
__device__ inline f32x4 mfma16k16(bf16x4 a, bf16x4 b, f32x4 c) {
    return __builtin_amdgcn_mfma_f32_16x16x16bf16_1k(
        __builtin_bit_cast(short4v, a), __builtin_bit_cast(short4v, b), c, 0, 0, 0);
}

__device__ inline void load_lds16(const void* g, void* l) {
    __builtin_amdgcn_global_load_lds(
        (__attribute__((address_space(1))) void*)g,
        (__attribute__((address_space(3))) void*)l, 16, 0, 0);
}

// ---------------- cast fp32 -> bf16, vectorized ----------------
__global__ __launch_bounds__(256) void cast_f32_bf16(const float* __restrict__ in,
                                                     __bf16* __restrict__ out) {
    size_t i = ((size_t)blockIdx.x * 256 + threadIdx.x) * 4;
    float4 v = *(const float4*)(in + i);
    bf16x4 o;
    o[0] = (__bf16)v.x; o[1] = (__bf16)v.y; o[2] = (__bf16)v.z; o[3] = (__bf16)v.w;
    *(bf16x4*)(out + i) = o;
}

// ---------------- transpose + cast: in [K][N] f32 -> out [N][K] bf16 ----------------
__global__ __launch_bounds__(256) void transpose_cast(const float* __restrict__ in,
                                                      __bf16* __restrict__ out,
                                                      int K, int N) {
    __shared__ float tile[32][33];
    int n0 = blockIdx.x * 32, k0 = blockIdx.y * 32;
    int tx = threadIdx.x, ty = threadIdx.y;   // block (32,8)
#pragma unroll
    for (int i = 0; i < 4; ++i)
        tile[ty + 8 * i][tx] = in[(size_t)(k0 + ty + 8 * i) * N + n0 + tx];
    __syncthreads();
#pragma unroll
    for (int i = 0; i < 4; ++i)
        out[(size_t)(n0 + ty + 8 * i) * K + k0 + tx] = (__bf16)tile[tx][ty + 8 * i];
}

// ---------------- V transpose: qkv V-section -> vt[b][h][d][s] bf16 ----------------
__global__ __launch_bounds__(256) void build_vt(const __bf16* __restrict__ qkv,
                                                __bf16* __restrict__ vt) {
    __shared__ __bf16 tile[64 * 72];   // [s][d] padded
    const int s0 = blockIdx.x * 64, h = blockIdx.y, b = blockIdx.z;
    const int tid = threadIdx.x;
#pragma unroll
    for (int r = 0; r < 2; ++r) {
        int c = r * 256 + tid;                 // 0..511
        int s = c >> 3, dp = c & 7;
        bf16x8 v = *(const bf16x8*)(qkv + (size_t)(b * SS + s0 + s) * QKV_N + 2048 + h * 64 + dp * 8);
        *(bf16x8*)(tile + s * 72 + dp * 8) = v;
    }
    __syncthreads();
#pragma unroll
    for (int r = 0; r < 2; ++r) {
        int c = r * 256 + tid;
        int d = c >> 3, sp = c & 7;
        bf16x8 o;
#pragma unroll
        for (int i = 0; i < 8; ++i) o[i] = tile[(sp * 8 + i) * 72 + d];
        *(bf16x8*)(vt + (size_t)((b * HH + h) * 64 + d) * SS + s0 + sp * 8) = o;
    }
}

// ---------------- GEMM: C[M][N] = A[M][K] @ Bt[N][K]^T + bias ----------------
// QSCALE: multiply columns [0,EE) by SCQ (folds attention scale into Q).
template <bool OUT_BF16, bool QSCALE>
__global__ __launch_bounds__(256) void gemm_bt(const __bf16* __restrict__ A,
                                               const __bf16* __restrict__ Bt,
                                               const float* __restrict__ bias,
                                               void* __restrict__ Cout,
                                               int M, int N, int K) {
    __shared__ __bf16 As[128 * 32];
    __shared__ __bf16 Bs[128 * 32];
    const int tid  = threadIdx.x;
    const int wave = tid >> 6;
    const int lane = tid & 63;
    const int lrow = lane & 15;
    const int quad = lane >> 4;
    const int wm   = (wave >> 1) * 64;
    const int wn   = (wave & 1) * 64;
    const int tm   = blockIdx.x * 128;
    const int tn   = blockIdx.y * 128;

    f32x4 acc[4][4] = {};

    const int srow = lane >> 2;
    const int skoff = (lane & 3) * 8;

    for (int k0 = 0; k0 < K; k0 += 32) {
        __syncthreads();
#pragma unroll
        for (int i = 0; i < 2; ++i) {
            int c = wave * 2 + i;
            int row = 16 * c + srow;
            load_lds16(A + (size_t)(tm + row) * K + k0 + skoff, As + c * 512);
            load_lds16(Bt + (size_t)(tn + row) * K + k0 + skoff, Bs + c * 512);
        }
        __syncthreads();

        bf16x8 bfr[4];
#pragma unroll
        for (int ni = 0; ni < 4; ++ni)
            bfr[ni] = *(const bf16x8*)(Bs + (wn + ni * 16 + lrow) * 32 + quad * 8);
#pragma unroll
        for (int mi = 0; mi < 4; ++mi) {
            bf16x8 a = *(const bf16x8*)(As + (wm + mi * 16 + lrow) * 32 + quad * 8);
#pragma unroll
            for (int ni = 0; ni < 4; ++ni)
                acc[mi][ni] = mfma16(a, bfr[ni], acc[mi][ni]);
        }
    }

#pragma unroll
    for (int ni = 0; ni < 4; ++ni) {
        int cn = tn + wn + ni * 16 + lrow;
        float bv = bias[cn];
        float sc = (QSCALE && cn < EE) ? SCQ : 1.0f;
#pragma unroll
        for (int mi = 0; mi < 4; ++mi) {
#pragma unroll
            for (int r = 0; r < 4; ++r) {
                int gm = tm + wm + mi * 16 + quad * 4 + r;
                float v = (acc[mi][ni][r] + bv) * sc;
                if (OUT_BF16)
                    ((__bf16*)Cout)[(size_t)gm * N + cn] = (__bf16)v;
                else
                    ((float*)Cout)[(size_t)gm * N + cn] = v;
            }
        }
    }
}

// ---------------- Flash attention v5 ----------------
// 128 q per block (2 groups/wave), 128-key LDS staging processed as two
// 64-key chunks (halves live S registers: R4's spill regression), K=16 PV
// consuming exp'd S registers directly. No min-wave launch bound.
__global__ __launch_bounds__(256) void attn5(const __bf16* __restrict__ qkv,
                                             const __bf16* __restrict__ vt,
                                             __bf16* __restrict__ y) {
    const int qt = gridDim.x - 1 - blockIdx.x;   // heavy blocks dispatch first
    const int h = blockIdx.y, b = blockIdx.z;
    const int tid = threadIdx.x;
    const int wave = tid >> 6, lane = tid & 63;
    const int lrow = lane & 15, quad = lane >> 4;
    const int qbase = qt * 128;

    __shared__ __bf16 Klds[128 * 64];   // [key][d-chunk8 ^ (key&7)]          16 KB
    __shared__ __bf16 Vlds[64 * 128];   // [d][k-chunk8: bit3 thru, ^ (d&7)]  16 KB

    const __bf16* kbase = qkv + (size_t)b * SS * QKV_N + 1024 + h * 64;
    const __bf16* vbase = vt + (size_t)(b * HH + h) * 64 * SS;

    // Q fragments (B-operand): q col = lrow; group g covers rows qbase+64g+16w+lrow
    bf16x8 qf[2][2];
#pragma unroll
    for (int g = 0; g < 2; ++g) {
        const __bf16* qp = qkv + (size_t)(b * SS + qbase + 64 * g + wave * 16 + lrow) * QKV_N + h * 64;
        qf[g][0] = *(const bf16x8*)(qp + quad * 8);
        qf[g][1] = *(const bf16x8*)(qp + 32 + quad * 8);
    }
    const int q0 = qbase + wave * 16 + lrow;   // group-0 q row for this lane's S col

    float m[2] = {-INFINITY, -INFINITY}, l[2] = {0.f, 0.f};
    f32x4 oacc[2][4] = {};   // O^T: d = 16*td + 4*quad + r, q col = lrow

    for (int kb_i = 0; kb_i <= qt; ++kb_i) {
        const int kb = kb_i * 128;
        const bool diag = (kb_i == qt);
        __syncthreads();
#pragma unroll
        for (int r = 0; r < 4; ++r) {          // stage K: 128 rows x 64 d
            int c = r * 256 + tid;
            int row = c >> 3;
            int g8 = ((c & 7) ^ (row & 7)) * 8;
            load_lds16(kbase + (size_t)(kb + row) * QKV_N + g8, Klds + c * 8);
        }
#pragma unroll
        for (int r = 0; r < 4; ++r) {          // stage V^T: 64 rows x 128 keys
            int c = r * 256 + tid;
            int d = c >> 4, kc = c & 15;
            int g8 = ((kc & 8) | ((kc & 7) ^ (d & 7))) * 8;
            load_lds16(vbase + (size_t)d * SS + kb + g8, Vlds + c * 8);
        }
        __syncthreads();

#pragma unroll
        for (int ch = 0; ch < 2; ++ch) {
            const bool do0 = !(diag && ch == 1);   // diag chunk1: group0 fully masked
            // QK^T chunk: 4 key tiles of 16
            f32x4 s0[4], s1[4];
#pragma unroll
            for (int t = 0; t < 4; ++t) {
                const __bf16* kr = Klds + (64 * ch + 16 * t + lrow) * 64;
                bf16x8 kf0 = *(const bf16x8*)(kr + 8 * (quad ^ (lrow & 7)));
                bf16x8 kf1 = *(const bf16x8*)(kr + 8 * ((4 + quad) ^ (lrow & 7)));
                f32x4 c1 = {};
                c1 = mfma16(kf0, qf[1][0], c1);
                c1 = mfma16(kf1, qf[1][1], c1);
                s1[t] = c1;
                if (do0) {
                    f32x4 c0 = {};
                    c0 = mfma16(kf0, qf[0][0], c0);
                    c0 = mfma16(kf1, qf[0][1], c0);
                    s0[t] = c0;
                }
            }
            if (diag) {
                if (ch == 0) {                 // group0 diagonal; group1 unmasked
#pragma unroll
                    for (int t = 0; t < 4; ++t)
#pragma unroll
                        for (int r = 0; r < 4; ++r)
                            if (kb + 16 * t + 4 * quad + r > q0) s0[t][r] = -INFINITY;
                } else {                       // group1 diagonal
#pragma unroll
                    for (int t = 0; t < 4; ++t)
#pragma unroll
                        for (int r = 0; r < 4; ++r)
                            if (kb + 64 + 16 * t + 4 * quad + r > q0 + 64) s1[t][r] = -INFINITY;
                }
            }

            // online softmax + pack P, per group
            bf16x4 p0[4], p1[4];
#pragma unroll
            for (int g = 0; g < 2; ++g) {
                if (g == 0 && !do0) continue;
                f32x4* s = g ? s1 : s0;
                bf16x4* p = g ? p1 : p0;
                float mx = -INFINITY;
#pragma unroll
                for (int t = 0; t < 4; ++t)
                    mx = fmaxf(mx, fmaxf(fmaxf(s[t][0], s[t][1]), fmaxf(s[t][2], s[t][3])));
                mx = fmaxf(mx, __shfl_xor(mx, 16));
                mx = fmaxf(mx, __shfl_xor(mx, 32));
                float mnew = fmaxf(m[g], mx);
                float alpha = exp2f(m[g] - mnew);
                m[g] = mnew;
                float rs = 0.f;
#pragma unroll
                for (int t = 0; t < 4; ++t) {
#pragma unroll
                    for (int r = 0; r < 4; ++r) {
                        float e = exp2f(s[t][r] - mnew);
                        rs += e;
                        p[t][r] = (__bf16)e;
                    }
                }
                rs += __shfl_xor(rs, 16);
                rs += __shfl_xor(rs, 32);
                l[g] = l[g] * alpha + rs;
#pragma unroll
                for (int td = 0; td < 4; ++td) {
                    oacc[g][td][0] *= alpha; oacc[g][td][1] *= alpha;
                    oacc[g][td][2] *= alpha; oacc[g][td][3] *= alpha;
                }
            }

            // PV: O^T += V^T P^T, K=16 per key tile; V frags shared across groups
#pragma unroll
            for (int t = 0; t < 4; ++t) {
                int klog = 8 * ch + 2 * t + (quad >> 1);
                int c = (klog & 8) | ((klog & 7) ^ (lrow & 7));
                const __bf16* vcol = Vlds + (size_t)lrow * 128 + c * 8 + 4 * (quad & 1);
#pragma unroll
                for (int td = 0; td < 4; ++td) {
                    bf16x4 vf = *(const bf16x4*)(vcol + td * 16 * 128);
                    oacc[1][td] = mfma16k16(vf, p1[t], oacc[1][td]);
                    if (do0) oacc[0][td] = mfma16k16(vf, p0[t], oacc[0][td]);
                }
            }
        }
    }

    // epilogue: y[q][h*64 + 16*td + 4*quad + r], packed 8B stores
#pragma unroll
    for (int g = 0; g < 2; ++g) {
        float linv = 1.f / l[g];
        __bf16* yp = y + (size_t)(b * SS + qbase + 64 * g + wave * 16 + lrow) * EE + h * 64;
#pragma unroll
        for (int td = 0; td < 4; ++td) {
            bf16x4 o;
#pragma unroll
            for (int r = 0; r < 4; ++r) o[r] = (__bf16)(oacc[g][td][r] * linv);
            *(bf16x4*)(yp + 16 * td + 4 * quad) = o;
        }
    }
}

// ---------------- launch ----------------
extern "C" void kernel_launch(void* const* d_in, const int* in_sizes, int n_in,
                              void* d_out, int out_size, void* d_ws, size_t ws_size,
                              hipStream_t stream) {
    const float* x      = (const float*)d_in[0];
    const float* w_qkv  = (const float*)d_in[1];
    const float* b_qkv  = (const float*)d_in[2];
    const float* w_proj = (const float*)d_in[3];
    const float* b_proj = (const float*)d_in[4];
    float* out = (float*)d_out;

    __bf16* xb     = (__bf16*)d_ws;                      // 16 MB (reused as vt later)
    __bf16* wqkvT  = xb + (size_t)ROWS * EE;             // [3072][1024]
    __bf16* wprojT = wqkvT + (size_t)QKV_N * EE;         // [1024][1024]
    __bf16* qkv    = wprojT + (size_t)EE * EE;           // [8192][3072]
    __bf16* yb     = qkv + (size_t)ROWS * QKV_N;         // [8192][1024]
    __bf16* vtb    = xb;                                 // alias: xb dead after GEMM1

    cast_f32_bf16<<<dim3(ROWS * EE / 1024), dim3(256), 0, stream>>>(x, xb);
    transpose_cast<<<dim3(QKV_N / 32, EE / 32), dim3(32, 8), 0, stream>>>(w_qkv, wqkvT, EE, QKV_N);
    transpose_cast<<<dim3(EE / 32, EE / 32), dim3(32, 8), 0, stream>>>(w_proj, wprojT, EE, EE);
    gemm_bt<true, true><<<dim3(ROWS / 128, QKV_N / 128), dim3(256), 0, stream>>>(
        xb, wqkvT, b_qkv, (void*)qkv, ROWS, QKV_N, EE);
    build_vt<<<dim3(SS / 64, HH, BB), dim3(256), 0, stream>>>(qkv, vtb);
    attn5<<<dim3(SS / 128, HH, BB), dim3(256), 0, stream>>>(qkv, vtb, yb);
    gemm_bt<false, false><<<dim3(ROWS / 128, EE / 128), dim3(256), 0, stream>>>(
        yb, wprojT, b_proj, (void*)out, ROWS, EE, EE);
}

// Round 6
// 309.202 us; speedup vs baseline: 1.5635x; 1.2228x over previous
//
#include <hip/hip_runtime.h>
#include <cmath>
#include <cstdint>

// Shapes (fixed for this problem)
#define BB 4
#define SS 2048
#define EE 1024
#define HH 16
#define DD 64
#define ROWS (BB*SS)          // 8192
#define QKV_N (3*EE)          // 3072
#define NQT 16                // S / 128 q-tiles

using bf16x8 = __attribute__((ext_vector_type(8))) __bf16;
using bf16x4 = __attribute__((ext_vector_type(4))) __bf16;
using f32x4  = __attribute__((ext_vector_type(4))) float;
typedef __attribute__((ext_vector_type(4))) short short4v;

// log2(e) / sqrt(64): folded into Q columns in the QKV GEMM epilogue
#define SCQ 0.18033688f

__device__ inline f32x4 mfma16(bf16x8 a, bf16x8 b, f32x4 c) {
    return __builtin_amdgcn_mfma_f32_16x16x32_bf16(a, b, c, 0, 0, 0);
}

// K=16 MFMA: B-operand layout (k=4*quad+j, n=lane&15) == C/D layout ->
// exp'd S registers feed PV directly, no cross-lane movement. (verified R4/R5)
__device__ inline f32x4 mfma16k16(bf16x4 a, bf16x4 b, f32x4 c) {
    return __builtin_amdgcn_mfma_f32_16x16x16bf16_1k(
        __builtin_bit_cast(short4v, a), __builtin_bit_cast(short4v, b), c, 0, 0, 0);
}

__device__ inline void load_lds16(const void* g, void* l) {
    __builtin_amdgcn_global_load_lds(
        (__attribute__((address_space(1))) void*)g,
        (__attribute__((address_space(3))) void*)l, 16, 0, 0);
}

// ---------------- cast fp32 -> bf16, vectorized ----------------
__global__ __launch_bounds__(256) void cast_f32_bf16(const float* __restrict__ in,
                                                     __bf16* __restrict__ out) {
    size_t i = ((size_t)blockIdx.x * 256 + threadIdx.x) * 4;
    float4 v = *(const float4*)(in + i);
    bf16x4 o;
    o[0] = (__bf16)v.x; o[1] = (__bf16)v.y; o[2] = (__bf16)v.z; o[3] = (__bf16)v.w;
    *(bf16x4*)(out + i) = o;
}

// ---------------- transpose + cast: in [K][N] f32 -> out [N][K] bf16 ----------------
__global__ __launch_bounds__(256) void transpose_cast(const float* __restrict__ in,
                                                      __bf16* __restrict__ out,
                                                      int K, int N) {
    __shared__ float tile[32][33];
    int n0 = blockIdx.x * 32, k0 = blockIdx.y * 32;
    int tx = threadIdx.x, ty = threadIdx.y;   // block (32,8)
#pragma unroll
    for (int i = 0; i < 4; ++i)
        tile[ty + 8 * i][tx] = in[(size_t)(k0 + ty + 8 * i) * N + n0 + tx];
    __syncthreads();
#pragma unroll
    for (int i = 0; i < 4; ++i)
        out[(size_t)(n0 + ty + 8 * i) * K + k0 + tx] = (__bf16)tile[tx][ty + 8 * i];
}

// ---------------- V transpose: qkv V-section -> vt[b][h][d][s] bf16 ----------------
__global__ __launch_bounds__(256) void build_vt(const __bf16* __restrict__ qkv,
                                                __bf16* __restrict__ vt) {
    __shared__ __bf16 tile[64 * 72];   // [s][d] padded
    const int s0 = blockIdx.x * 64, h = blockIdx.y, b = blockIdx.z;
    const int tid = threadIdx.x;
#pragma unroll
    for (int r = 0; r < 2; ++r) {
        int c = r * 256 + tid;                 // 0..511
        int s = c >> 3, dp = c & 7;
        bf16x8 v = *(const bf16x8*)(qkv + (size_t)(b * SS + s0 + s) * QKV_N + 2048 + h * 64 + dp * 8);
        *(bf16x8*)(tile + s * 72 + dp * 8) = v;
    }
    __syncthreads();
#pragma unroll
    for (int r = 0; r < 2; ++r) {
        int c = r * 256 + tid;
        int d = c >> 3, sp = c & 7;
        bf16x8 o;
#pragma unroll
        for (int i = 0; i < 8; ++i) o[i] = tile[(sp * 8 + i) * 72 + d];
        *(bf16x8*)(vt + (size_t)((b * HH + h) * 64 + d) * SS + s0 + sp * 8) = o;
    }
}

// ---------------- GEMM: C[M][N] = A[M][K] @ Bt[N][K]^T + bias ----------------
// QSCALE: multiply columns [0,EE) by SCQ (folds attention scale into Q).
template <bool OUT_BF16, bool QSCALE>
__global__ __launch_bounds__(256) void gemm_bt(const __bf16* __restrict__ A,
                                               const __bf16* __restrict__ Bt,
                                               const float* __restrict__ bias,
                                               void* __restrict__ Cout,
                                               int M, int N, int K) {
    __shared__ __bf16 As[128 * 32];
    __shared__ __bf16 Bs[128 * 32];
    const int tid  = threadIdx.x;
    const int wave = tid >> 6;
    const int lane = tid & 63;
    const int lrow = lane & 15;
    const int quad = lane >> 4;
    const int wm   = (wave >> 1) * 64;
    const int wn   = (wave & 1) * 64;
    const int tm   = blockIdx.x * 128;
    const int tn   = blockIdx.y * 128;

    f32x4 acc[4][4] = {};

    const int srow = lane >> 2;
    const int skoff = (lane & 3) * 8;

    for (int k0 = 0; k0 < K; k0 += 32) {
        __syncthreads();
#pragma unroll
        for (int i = 0; i < 2; ++i) {
            int c = wave * 2 + i;
            int row = 16 * c + srow;
            load_lds16(A + (size_t)(tm + row) * K + k0 + skoff, As + c * 512);
            load_lds16(Bt + (size_t)(tn + row) * K + k0 + skoff, Bs + c * 512);
        }
        __syncthreads();

        bf16x8 bfr[4];
#pragma unroll
        for (int ni = 0; ni < 4; ++ni)
            bfr[ni] = *(const bf16x8*)(Bs + (wn + ni * 16 + lrow) * 32 + quad * 8);
#pragma unroll
        for (int mi = 0; mi < 4; ++mi) {
            bf16x8 a = *(const bf16x8*)(As + (wm + mi * 16 + lrow) * 32 + quad * 8);
#pragma unroll
            for (int ni = 0; ni < 4; ++ni)
                acc[mi][ni] = mfma16(a, bfr[ni], acc[mi][ni]);
        }
    }

#pragma unroll
    for (int ni = 0; ni < 4; ++ni) {
        int cn = tn + wn + ni * 16 + lrow;
        float bv = bias[cn];
        float sc = (QSCALE && cn < EE) ? SCQ : 1.0f;
#pragma unroll
        for (int mi = 0; mi < 4; ++mi) {
#pragma unroll
            for (int r = 0; r < 4; ++r) {
                int gm = tm + wm + mi * 16 + quad * 4 + r;
                float v = (acc[mi][ni][r] + bv) * sc;
                if (OUT_BF16)
                    ((__bf16*)Cout)[(size_t)gm * N + cn] = (__bf16)v;
                else
                    ((float*)Cout)[(size_t)gm * N + cn] = v;
            }
        }
    }
}

// stage one 128-key K tile + V^T tile into the given LDS buffers (XOR-swizzled)
__device__ __forceinline__ void stage_kv(const __bf16* __restrict__ kbase,
                                         const __bf16* __restrict__ vbase,
                                         __bf16* Kb, __bf16* Vb, int kb, int tid) {
#pragma unroll
    for (int r = 0; r < 4; ++r) {          // K: 128 rows x 64 d
        int c = r * 256 + tid;
        int row = c >> 3;
        int g8 = ((c & 7) ^ (row & 7)) * 8;
        load_lds16(kbase + (size_t)(kb + row) * QKV_N + g8, Kb + c * 8);
    }
#pragma unroll
    for (int r = 0; r < 4; ++r) {          // V^T: 64 rows x 128 keys
        int c = r * 256 + tid;
        int d = c >> 4, kc = c & 15;
        int g8 = ((kc & 8) | ((kc & 7) ^ (d & 7))) * 8;
        load_lds16(vbase + (size_t)d * SS + kb + g8, Vb + c * 8);
    }
}

// ---------------- Flash attention v6 ----------------
// Triangle pairing: block j handles q-tiles (NQT-1-j) then (j) => 17 iters/block,
// 512 blocks = exactly 2/CU, zero imbalance. Double-buffered K/V staging (64 KB):
// prefetch iter i+1 right after the barrier, compute iter i meanwhile.
__global__ __launch_bounds__(256) void attn6(const __bf16* __restrict__ qkv,
                                             const __bf16* __restrict__ vt,
                                             __bf16* __restrict__ y) {
    const int j = blockIdx.x;                  // 0..NQT/2-1
    const int h = blockIdx.y, b = blockIdx.z;
    const int tid = threadIdx.x;
    const int wave = tid >> 6, lane = tid & 63;
    const int lrow = lane & 15, quad = lane >> 4;

    __shared__ __bf16 Klds[2][128 * 64];   // [key][d-chunk8 ^ (key&7)]          2x16 KB
    __shared__ __bf16 Vlds[2][64 * 128];   // [d][k-chunk8: bit3 thru, ^ (d&7)]  2x16 KB

    const __bf16* kbase = qkv + (size_t)b * SS * QKV_N + 1024 + h * 64;
    const __bf16* vbase = vt + (size_t)(b * HH + h) * 64 * SS;

    const int qtA = NQT - 1 - j, qtB = j;
    const int nA = qtA + 1, total = nA + qtB + 1;

    stage_kv(kbase, vbase, Klds[0], Vlds[0], 0, tid);   // prime buffer 0

    int it = 0;
    for (int seg = 0; seg < 2; ++seg) {
        const int qtile = seg ? qtB : qtA;
        const int qbase = qtile * 128;

        // Q fragments (B-operand): q col = lrow; group g -> rows qbase+64g+16w+lrow
        bf16x8 qf[2][2];
#pragma unroll
        for (int g = 0; g < 2; ++g) {
            const __bf16* qp = qkv + (size_t)(b * SS + qbase + 64 * g + wave * 16 + lrow) * QKV_N + h * 64;
            qf[g][0] = *(const bf16x8*)(qp + quad * 8);
            qf[g][1] = *(const bf16x8*)(qp + 32 + quad * 8);
        }
        const int q0 = qbase + wave * 16 + lrow;

        float m[2] = {-INFINITY, -INFINITY}, l[2] = {0.f, 0.f};
        f32x4 oacc[2][4] = {};   // O^T: d = 16*td + 4*quad + r, q col = lrow

        for (int kb_i = 0; kb_i <= qtile; ++kb_i, ++it) {
            const int cur = it & 1;
            const int kb = kb_i * 128;
            const bool diag = (kb_i == qtile);
            __syncthreads();   // buf[cur] staged; all waves done with buf[cur^1]
            if (it + 1 < total) {
                int nit = it + 1;
                int nkb = (nit < nA ? nit : nit - nA) * 128;
                stage_kv(kbase, vbase, Klds[cur ^ 1], Vlds[cur ^ 1], nkb, tid);
            }
            const __bf16* Kb = Klds[cur];
            const __bf16* Vb = Vlds[cur];

#pragma unroll
            for (int ch = 0; ch < 2; ++ch) {
                const bool do0 = !(diag && ch == 1);   // diag chunk1: group0 fully masked
                // QK^T chunk: 4 key tiles of 16
                f32x4 s0[4], s1[4];
#pragma unroll
                for (int t = 0; t < 4; ++t) {
                    const __bf16* kr = Kb + (64 * ch + 16 * t + lrow) * 64;
                    bf16x8 kf0 = *(const bf16x8*)(kr + 8 * (quad ^ (lrow & 7)));
                    bf16x8 kf1 = *(const bf16x8*)(kr + 8 * ((4 + quad) ^ (lrow & 7)));
                    f32x4 c1 = {};
                    c1 = mfma16(kf0, qf[1][0], c1);
                    c1 = mfma16(kf1, qf[1][1], c1);
                    s1[t] = c1;
                    if (do0) {
                        f32x4 c0 = {};
                        c0 = mfma16(kf0, qf[0][0], c0);
                        c0 = mfma16(kf1, qf[0][1], c0);
                        s0[t] = c0;
                    }
                }
                if (diag) {
                    if (ch == 0) {                 // group0 diagonal; group1 unmasked
#pragma unroll
                        for (int t = 0; t < 4; ++t)
#pragma unroll
                            for (int r = 0; r < 4; ++r)
                                if (kb + 16 * t + 4 * quad + r > q0) s0[t][r] = -INFINITY;
                    } else {                       // group1 diagonal
#pragma unroll
                        for (int t = 0; t < 4; ++t)
#pragma unroll
                            for (int r = 0; r < 4; ++r)
                                if (kb + 64 + 16 * t + 4 * quad + r > q0 + 64) s1[t][r] = -INFINITY;
                    }
                }

                // online softmax + pack P, per group
                bf16x4 p0[4], p1[4];
#pragma unroll
                for (int g = 0; g < 2; ++g) {
                    if (g == 0 && !do0) continue;
                    f32x4* s = g ? s1 : s0;
                    bf16x4* p = g ? p1 : p0;
                    float mx = -INFINITY;
#pragma unroll
                    for (int t = 0; t < 4; ++t)
                        mx = fmaxf(mx, fmaxf(fmaxf(s[t][0], s[t][1]), fmaxf(s[t][2], s[t][3])));
                    mx = fmaxf(mx, __shfl_xor(mx, 16));
                    mx = fmaxf(mx, __shfl_xor(mx, 32));
                    float mnew = fmaxf(m[g], mx);
                    float alpha = exp2f(m[g] - mnew);
                    m[g] = mnew;
                    float rs = 0.f;
#pragma unroll
                    for (int t = 0; t < 4; ++t) {
#pragma unroll
                        for (int r = 0; r < 4; ++r) {
                            float e = exp2f(s[t][r] - mnew);
                            rs += e;
                            p[t][r] = (__bf16)e;
                        }
                    }
                    rs += __shfl_xor(rs, 16);
                    rs += __shfl_xor(rs, 32);
                    l[g] = l[g] * alpha + rs;
#pragma unroll
                    for (int td = 0; td < 4; ++td) {
                        oacc[g][td][0] *= alpha; oacc[g][td][1] *= alpha;
                        oacc[g][td][2] *= alpha; oacc[g][td][3] *= alpha;
                    }
                }

                // PV: O^T += V^T P^T, K=16 per key tile; V frags shared across groups
#pragma unroll
                for (int t = 0; t < 4; ++t) {
                    int klog = 8 * ch + 2 * t + (quad >> 1);
                    int c = (klog & 8) | ((klog & 7) ^ (lrow & 7));
                    const __bf16* vcol = Vb + (size_t)lrow * 128 + c * 8 + 4 * (quad & 1);
#pragma unroll
                    for (int td = 0; td < 4; ++td) {
                        bf16x4 vf = *(const bf16x4*)(vcol + td * 16 * 128);
                        oacc[1][td] = mfma16k16(vf, p1[t], oacc[1][td]);
                        if (do0) oacc[0][td] = mfma16k16(vf, p0[t], oacc[0][td]);
                    }
                }
            }
        }

        // epilogue: y[q][h*64 + 16*td + 4*quad + r], packed 8B stores
#pragma unroll
        for (int g = 0; g < 2; ++g) {
            float linv = 1.f / l[g];
            __bf16* yp = y + (size_t)(b * SS + qbase + 64 * g + wave * 16 + lrow) * EE + h * 64;
#pragma unroll
            for (int td = 0; td < 4; ++td) {
                bf16x4 o;
#pragma unroll
                for (int r = 0; r < 4; ++r) o[r] = (__bf16)(oacc[g][td][r] * linv);
                *(bf16x4*)(yp + 16 * td + 4 * quad) = o;
            }
        }
    }
}

// ---------------- launch ----------------
extern "C" void kernel_launch(void* const* d_in, const int* in_sizes, int n_in,
                              void* d_out, int out_size, void* d_ws, size_t ws_size,
                              hipStream_t stream) {
    const float* x      = (const float*)d_in[0];
    const float* w_qkv  = (const float*)d_in[1];
    const float* b_qkv  = (const float*)d_in[2];
    const float* w_proj = (const float*)d_in[3];
    const float* b_proj = (const float*)d_in[4];
    float* out = (float*)d_out;

    __bf16* xb     = (__bf16*)d_ws;                      // 16 MB (reused as vt later)
    __bf16* wqkvT  = xb + (size_t)ROWS * EE;             // [3072][1024]
    __bf16* wprojT = wqkvT + (size_t)QKV_N * EE;         // [1024][1024]
    __bf16* qkv    = wprojT + (size_t)EE * EE;           // [8192][3072]
    __bf16* yb     = qkv + (size_t)ROWS * QKV_N;         // [8192][1024]
    __bf16* vtb    = xb;                                 // alias: xb dead after GEMM1

    cast_f32_bf16<<<dim3(ROWS * EE / 1024), dim3(256), 0, stream>>>(x, xb);
    transpose_cast<<<dim3(QKV_N / 32, EE / 32), dim3(32, 8), 0, stream>>>(w_qkv, wqkvT, EE, QKV_N);
    transpose_cast<<<dim3(EE / 32, EE / 32), dim3(32, 8), 0, stream>>>(w_proj, wprojT, EE, EE);
    gemm_bt<true, true><<<dim3(ROWS / 128, QKV_N / 128), dim3(256), 0, stream>>>(
        xb, wqkvT, b_qkv, (void*)qkv, ROWS, QKV_N, EE);
    build_vt<<<dim3(SS / 64, HH, BB), dim3(256), 0, stream>>>(qkv, vtb);
    attn6<<<dim3(NQT / 2, HH, BB), dim3(256), 0, stream>>>(qkv, vtb, yb);
    gemm_bt<false, false><<<dim3(ROWS / 128, EE / 128), dim3(256), 0, stream>>>(
        yb, wprojT, b_proj, (void*)out, ROWS, EE, EE);
}

// Round 7
// 301.753 us; speedup vs baseline: 1.6021x; 1.0247x over previous
//
#include <hip/hip_runtime.h>
#include <cmath>
#include <cstdint>

// Shapes (fixed for this problem)
#define BB 4
#define SS 2048
#define EE 1024
#define HH 16
#define DD 64
#define ROWS (BB*SS)          // 8192
#define QKV_N (3*EE)          // 3072
#define NQT 16                // S / 128 q-tiles

using bf16x8 = __attribute__((ext_vector_type(8))) __bf16;
using bf16x4 = __attribute__((ext_vector_type(4))) __bf16;
using f32x4  = __attribute__((ext_vector_type(4))) float;
typedef __attribute__((ext_vector_type(4))) short short4v;

// log2(e) / sqrt(64): folded into Q columns in the QKV GEMM epilogue
#define SCQ 0.18033688f

__device__ inline f32x4 mfma16(bf16x8 a, bf16x8 b, f32x4 c) {
    return __builtin_amdgcn_mfma_f32_16x16x32_bf16(a, b, c, 0, 0, 0);
}

// K=16 MFMA: B-operand layout (k=4*quad+j, n=lane&15) == C/D layout ->
// exp'd S registers feed PV directly, no cross-lane movement. (verified R4/R5/R6)
__device__ inline f32x4 mfma16k16(bf16x4 a, bf16x4 b, f32x4 c) {
    return __builtin_amdgcn_mfma_f32_16x16x16bf16_1k(
        __builtin_bit_cast(short4v, a), __builtin_bit_cast(short4v, b), c, 0, 0, 0);
}

__device__ inline void load_lds16(const void* g, void* l) {
    __builtin_amdgcn_global_load_lds(
        (__attribute__((address_space(1))) void*)g,
        (__attribute__((address_space(3))) void*)l, 16, 0, 0);
}

// ---------------- cast fp32 -> bf16, vectorized ----------------
__global__ __launch_bounds__(256) void cast_f32_bf16(const float* __restrict__ in,
                                                     __bf16* __restrict__ out) {
    size_t i = ((size_t)blockIdx.x * 256 + threadIdx.x) * 4;
    float4 v = *(const float4*)(in + i);
    bf16x4 o;
    o[0] = (__bf16)v.x; o[1] = (__bf16)v.y; o[2] = (__bf16)v.z; o[3] = (__bf16)v.w;
    *(bf16x4*)(out + i) = o;
}

// ---------------- transpose + cast: in [K][N] f32 -> out [N][K] bf16 ----------------
__global__ __launch_bounds__(256) void transpose_cast(const float* __restrict__ in,
                                                      __bf16* __restrict__ out,
                                                      int K, int N) {
    __shared__ float tile[32][33];
    int n0 = blockIdx.x * 32, k0 = blockIdx.y * 32;
    int tx = threadIdx.x, ty = threadIdx.y;   // block (32,8)
#pragma unroll
    for (int i = 0; i < 4; ++i)
        tile[ty + 8 * i][tx] = in[(size_t)(k0 + ty + 8 * i) * N + n0 + tx];
    __syncthreads();
#pragma unroll
    for (int i = 0; i < 4; ++i)
        out[(size_t)(n0 + ty + 8 * i) * K + k0 + tx] = (__bf16)tile[tx][ty + 8 * i];
}

// ---------------- V transpose: qkv V-section -> vt[b][h][d][s] bf16 ----------------
__global__ __launch_bounds__(256) void build_vt(const __bf16* __restrict__ qkv,
                                                __bf16* __restrict__ vt) {
    __shared__ __bf16 tile[64 * 72];   // [s][d] padded
    const int s0 = blockIdx.x * 64, h = blockIdx.y, b = blockIdx.z;
    const int tid = threadIdx.x;
#pragma unroll
    for (int r = 0; r < 2; ++r) {
        int c = r * 256 + tid;                 // 0..511
        int s = c >> 3, dp = c & 7;
        bf16x8 v = *(const bf16x8*)(qkv + (size_t)(b * SS + s0 + s) * QKV_N + 2048 + h * 64 + dp * 8);
        *(bf16x8*)(tile + s * 72 + dp * 8) = v;
    }
    __syncthreads();
#pragma unroll
    for (int r = 0; r < 2; ++r) {
        int c = r * 256 + tid;
        int d = c >> 3, sp = c & 7;
        bf16x8 o;
#pragma unroll
        for (int i = 0; i < 8; ++i) o[i] = tile[(sp * 8 + i) * 72 + d];
        *(bf16x8*)(vt + (size_t)((b * HH + h) * 64 + d) * SS + s0 + sp * 8) = o;
    }
}

// ---------------- GEMM: C[M][N] = A[M][K] @ Bt[N][K]^T + bias ----------------
// QSCALE: multiply columns [0,EE) by SCQ (folds attention scale into Q).
template <bool OUT_BF16, bool QSCALE>
__global__ __launch_bounds__(256) void gemm_bt(const __bf16* __restrict__ A,
                                               const __bf16* __restrict__ Bt,
                                               const float* __restrict__ bias,
                                               void* __restrict__ Cout,
                                               int M, int N, int K) {
    __shared__ __bf16 As[128 * 32];
    __shared__ __bf16 Bs[128 * 32];
    const int tid  = threadIdx.x;
    const int wave = tid >> 6;
    const int lane = tid & 63;
    const int lrow = lane & 15;
    const int quad = lane >> 4;
    const int wm   = (wave >> 1) * 64;
    const int wn   = (wave & 1) * 64;
    const int tm   = blockIdx.x * 128;
    const int tn   = blockIdx.y * 128;

    f32x4 acc[4][4] = {};

    const int srow = lane >> 2;
    const int skoff = (lane & 3) * 8;

    for (int k0 = 0; k0 < K; k0 += 32) {
        __syncthreads();
#pragma unroll
        for (int i = 0; i < 2; ++i) {
            int c = wave * 2 + i;
            int row = 16 * c + srow;
            load_lds16(A + (size_t)(tm + row) * K + k0 + skoff, As + c * 512);
            load_lds16(Bt + (size_t)(tn + row) * K + k0 + skoff, Bs + c * 512);
        }
        __syncthreads();

        bf16x8 bfr[4];
#pragma unroll
        for (int ni = 0; ni < 4; ++ni)
            bfr[ni] = *(const bf16x8*)(Bs + (wn + ni * 16 + lrow) * 32 + quad * 8);
#pragma unroll
        for (int mi = 0; mi < 4; ++mi) {
            bf16x8 a = *(const bf16x8*)(As + (wm + mi * 16 + lrow) * 32 + quad * 8);
#pragma unroll
            for (int ni = 0; ni < 4; ++ni)
                acc[mi][ni] = mfma16(a, bfr[ni], acc[mi][ni]);
        }
    }

#pragma unroll
    for (int ni = 0; ni < 4; ++ni) {
        int cn = tn + wn + ni * 16 + lrow;
        float bv = bias[cn];
        float sc = (QSCALE && cn < EE) ? SCQ : 1.0f;
#pragma unroll
        for (int mi = 0; mi < 4; ++mi) {
#pragma unroll
            for (int r = 0; r < 4; ++r) {
                int gm = tm + wm + mi * 16 + quad * 4 + r;
                float v = (acc[mi][ni][r] + bv) * sc;
                if (OUT_BF16)
                    ((__bf16*)Cout)[(size_t)gm * N + cn] = (__bf16)v;
                else
                    ((float*)Cout)[(size_t)gm * N + cn] = v;
            }
        }
    }
}

// stage one 128-key K tile + V^T tile into the given LDS buffers (XOR-swizzled)
__device__ __forceinline__ void stage_kv(const __bf16* __restrict__ kbase,
                                         const __bf16* __restrict__ vbase,
                                         __bf16* Kb, __bf16* Vb, int kb, int tid) {
#pragma unroll
    for (int r = 0; r < 4; ++r) {          // K: 128 rows x 64 d
        int c = r * 256 + tid;
        int row = c >> 3;
        int g8 = ((c & 7) ^ (row & 7)) * 8;
        load_lds16(kbase + (size_t)(kb + row) * QKV_N + g8, Kb + c * 8);
    }
#pragma unroll
    for (int r = 0; r < 4; ++r) {          // V^T: 64 rows x 128 keys
        int c = r * 256 + tid;
        int d = c >> 4, kc = c & 15;
        int g8 = ((kc & 8) | ((kc & 7) ^ (d & 7))) * 8;
        load_lds16(vbase + (size_t)d * SS + kb + g8, Vb + c * 8);
    }
}

// ---------------- Flash attention v7 ----------------
// v6 + XCD-locality grid: grid (64 hb, 8 j). Linear block id = hb + 64*j, so
// XCD = id % 8 = hb % 8 -> all 8 j-blocks sharing one (b,h)'s K/V stream land
// on ONE XCD and read tile kb in near-lockstep => L2 fetches each tile once
// (v6 had XCD = j: 8 XCDs each fetched the same tiles -> FETCH 147 MB).
__global__ __launch_bounds__(256) void attn7(const __bf16* __restrict__ qkv,
                                             const __bf16* __restrict__ vt,
                                             __bf16* __restrict__ y) {
    const int hb = blockIdx.x;                 // fast dim: h + 16*b
    const int h = hb & 15, b = hb >> 4;
    const int j = blockIdx.y;                  // 0..NQT/2-1
    const int tid = threadIdx.x;
    const int wave = tid >> 6, lane = tid & 63;
    const int lrow = lane & 15, quad = lane >> 4;

    __shared__ __bf16 Klds[2][128 * 64];   // [key][d-chunk8 ^ (key&7)]          2x16 KB
    __shared__ __bf16 Vlds[2][64 * 128];   // [d][k-chunk8: bit3 thru, ^ (d&7)]  2x16 KB

    const __bf16* kbase = qkv + (size_t)b * SS * QKV_N + 1024 + h * 64;
    const __bf16* vbase = vt + (size_t)(b * HH + h) * 64 * SS;

    const int qtA = NQT - 1 - j, qtB = j;
    const int nA = qtA + 1, total = nA + qtB + 1;

    stage_kv(kbase, vbase, Klds[0], Vlds[0], 0, tid);   // prime buffer 0

    int it = 0;
    for (int seg = 0; seg < 2; ++seg) {
        const int qtile = seg ? qtB : qtA;
        const int qbase = qtile * 128;

        // Q fragments (B-operand): q col = lrow; group g -> rows qbase+64g+16w+lrow
        bf16x8 qf[2][2];
#pragma unroll
        for (int g = 0; g < 2; ++g) {
            const __bf16* qp = qkv + (size_t)(b * SS + qbase + 64 * g + wave * 16 + lrow) * QKV_N + h * 64;
            qf[g][0] = *(const bf16x8*)(qp + quad * 8);
            qf[g][1] = *(const bf16x8*)(qp + 32 + quad * 8);
        }
        const int q0 = qbase + wave * 16 + lrow;

        float m[2] = {-INFINITY, -INFINITY}, l[2] = {0.f, 0.f};
        f32x4 oacc[2][4] = {};   // O^T: d = 16*td + 4*quad + r, q col = lrow

        for (int kb_i = 0; kb_i <= qtile; ++kb_i, ++it) {
            const int cur = it & 1;
            const int kb = kb_i * 128;
            const bool diag = (kb_i == qtile);
            __syncthreads();   // buf[cur] staged; all waves done with buf[cur^1]
            if (it + 1 < total) {
                int nit = it + 1;
                int nkb = (nit < nA ? nit : nit - nA) * 128;
                stage_kv(kbase, vbase, Klds[cur ^ 1], Vlds[cur ^ 1], nkb, tid);
            }
            const __bf16* Kb = Klds[cur];
            const __bf16* Vb = Vlds[cur];

#pragma unroll
            for (int ch = 0; ch < 2; ++ch) {
                const bool do0 = !(diag && ch == 1);   // diag chunk1: group0 fully masked
                // QK^T chunk: 4 key tiles of 16
                f32x4 s0[4], s1[4];
#pragma unroll
                for (int t = 0; t < 4; ++t) {
                    const __bf16* kr = Kb + (64 * ch + 16 * t + lrow) * 64;
                    bf16x8 kf0 = *(const bf16x8*)(kr + 8 * (quad ^ (lrow & 7)));
                    bf16x8 kf1 = *(const bf16x8*)(kr + 8 * ((4 + quad) ^ (lrow & 7)));
                    f32x4 c1 = {};
                    c1 = mfma16(kf0, qf[1][0], c1);
                    c1 = mfma16(kf1, qf[1][1], c1);
                    s1[t] = c1;
                    if (do0) {
                        f32x4 c0 = {};
                        c0 = mfma16(kf0, qf[0][0], c0);
                        c0 = mfma16(kf1, qf[0][1], c0);
                        s0[t] = c0;
                    }
                }
                if (diag) {
                    if (ch == 0) {                 // group0 diagonal; group1 unmasked
#pragma unroll
                        for (int t = 0; t < 4; ++t)
#pragma unroll
                            for (int r = 0; r < 4; ++r)
                                if (kb + 16 * t + 4 * quad + r > q0) s0[t][r] = -INFINITY;
                    } else {                       // group1 diagonal
#pragma unroll
                        for (int t = 0; t < 4; ++t)
#pragma unroll
                            for (int r = 0; r < 4; ++r)
                                if (kb + 64 + 16 * t + 4 * quad + r > q0 + 64) s1[t][r] = -INFINITY;
                    }
                }

                // online softmax + pack P, per group
                bf16x4 p0[4], p1[4];
#pragma unroll
                for (int g = 0; g < 2; ++g) {
                    if (g == 0 && !do0) continue;
                    f32x4* s = g ? s1 : s0;
                    bf16x4* p = g ? p1 : p0;
                    float mx = -INFINITY;
#pragma unroll
                    for (int t = 0; t < 4; ++t)
                        mx = fmaxf(mx, fmaxf(fmaxf(s[t][0], s[t][1]), fmaxf(s[t][2], s[t][3])));
                    mx = fmaxf(mx, __shfl_xor(mx, 16));
                    mx = fmaxf(mx, __shfl_xor(mx, 32));
                    float mnew = fmaxf(m[g], mx);
                    float alpha = exp2f(m[g] - mnew);
                    m[g] = mnew;
                    float rs = 0.f;
#pragma unroll
                    for (int t = 0; t < 4; ++t) {
#pragma unroll
                        for (int r = 0; r < 4; ++r) {
                            float e = exp2f(s[t][r] - mnew);
                            rs += e;
                            p[t][r] = (__bf16)e;
                        }
                    }
                    rs += __shfl_xor(rs, 16);
                    rs += __shfl_xor(rs, 32);
                    l[g] = l[g] * alpha + rs;
#pragma unroll
                    for (int td = 0; td < 4; ++td) {
                        oacc[g][td][0] *= alpha; oacc[g][td][1] *= alpha;
                        oacc[g][td][2] *= alpha; oacc[g][td][3] *= alpha;
                    }
                }

                // PV: O^T += V^T P^T, K=16 per key tile; V frags shared across groups
#pragma unroll
                for (int t = 0; t < 4; ++t) {
                    int klog = 8 * ch + 2 * t + (quad >> 1);
                    int c = (klog & 8) | ((klog & 7) ^ (lrow & 7));
                    const __bf16* vcol = Vb + (size_t)lrow * 128 + c * 8 + 4 * (quad & 1);
#pragma unroll
                    for (int td = 0; td < 4; ++td) {
                        bf16x4 vf = *(const bf16x4*)(vcol + td * 16 * 128);
                        oacc[1][td] = mfma16k16(vf, p1[t], oacc[1][td]);
                        if (do0) oacc[0][td] = mfma16k16(vf, p0[t], oacc[0][td]);
                    }
                }
            }
        }

        // epilogue: y[q][h*64 + 16*td + 4*quad + r], packed 8B stores
#pragma unroll
        for (int g = 0; g < 2; ++g) {
            float linv = 1.f / l[g];
            __bf16* yp = y + (size_t)(b * SS + qbase + 64 * g + wave * 16 + lrow) * EE + h * 64;
#pragma unroll
            for (int td = 0; td < 4; ++td) {
                bf16x4 o;
#pragma unroll
                for (int r = 0; r < 4; ++r) o[r] = (__bf16)(oacc[g][td][r] * linv);
                *(bf16x4*)(yp + 16 * td + 4 * quad) = o;
            }
        }
    }
}

// ---------------- launch ----------------
extern "C" void kernel_launch(void* const* d_in, const int* in_sizes, int n_in,
                              void* d_out, int out_size, void* d_ws, size_t ws_size,
                              hipStream_t stream) {
    const float* x      = (const float*)d_in[0];
    const float* w_qkv  = (const float*)d_in[1];
    const float* b_qkv  = (const float*)d_in[2];
    const float* w_proj = (const float*)d_in[3];
    const float* b_proj = (const float*)d_in[4];
    float* out = (float*)d_out;

    __bf16* xb     = (__bf16*)d_ws;                      // 16 MB (reused as vt later)
    __bf16* wqkvT  = xb + (size_t)ROWS * EE;             // [3072][1024]
    __bf16* wprojT = wqkvT + (size_t)QKV_N * EE;         // [1024][1024]
    __bf16* qkv    = wprojT + (size_t)EE * EE;           // [8192][3072]
    __bf16* yb     = qkv + (size_t)ROWS * QKV_N;         // [8192][1024]
    __bf16* vtb    = xb;                                 // alias: xb dead after GEMM1

    cast_f32_bf16<<<dim3(ROWS * EE / 1024), dim3(256), 0, stream>>>(x, xb);
    transpose_cast<<<dim3(QKV_N / 32, EE / 32), dim3(32, 8), 0, stream>>>(w_qkv, wqkvT, EE, QKV_N);
    transpose_cast<<<dim3(EE / 32, EE / 32), dim3(32, 8), 0, stream>>>(w_proj, wprojT, EE, EE);
    gemm_bt<true, true><<<dim3(ROWS / 128, QKV_N / 128), dim3(256), 0, stream>>>(
        xb, wqkvT, b_qkv, (void*)qkv, ROWS, QKV_N, EE);
    build_vt<<<dim3(SS / 64, HH, BB), dim3(256), 0, stream>>>(qkv, vtb);
    attn7<<<dim3(HH * BB, NQT / 2), dim3(256), 0, stream>>>(qkv, vtb, yb);
    gemm_bt<false, false><<<dim3(ROWS / 128, EE / 128), dim3(256), 0, stream>>>(
        yb, wprojT, b_proj, (void*)out, ROWS, EE, EE);
}